// Round 5
// baseline (1833.999 us; speedup 1.0000x reference)
//
#include <hip/hip_runtime.h>

typedef __attribute__((ext_vector_type(8))) short bf16x8;
typedef __attribute__((ext_vector_type(4))) float f32x4;
typedef __attribute__((ext_vector_type(2))) _Float16 f16x2;

#define MFMA(a, b, c) __builtin_amdgcn_mfma_f32_16x16x32_bf16((a), (b), (c), 0, 0, 0)

__device__ __forceinline__ unsigned short f2bf(float f) {
    unsigned int u = __builtin_bit_cast(unsigned int, f);
    return (unsigned short)((u + 0x7FFFu + ((u >> 16) & 1u)) >> 16);  // RNE
}

// B=512, S=128, I=64, H=256, C=10
// 256 blocks (2 batch rows each) x 512 threads (8 waves), 1 block/CU.
//
// R1-R4 forensics: the backend's occupancy heuristic pinned the budget at 128
// VGPR (512T) / 64 (1024T) regardless of launch_bounds, waves_per_eu, or LDS
// sizing -> the 192-VGPR weight set spilled, loop re-reads spills from L2 at
// ~29 TB/s (= the 1.8 ms plateau). amdgpu_num_vgpr(256) sets the
// "amdgpu-num-vgpr" fn attribute, which getMaxNumVGPRs returns DIRECTLY,
// bypassing the heuristic. 2 waves/SIMD x 256 = 512 = full pool, feasible.
// LDS kept > 80 KB so a second block can never co-reside.
__global__ __launch_bounds__(512)
__attribute__((amdgpu_num_vgpr(256), amdgpu_waves_per_eu(2, 2)))
void ltc_kernel(
    const float* __restrict__ x, const float* __restrict__ W_gd,
    const float* __restrict__ b_gd, const float* __restrict__ W_tau,
    const float* __restrict__ b_tau, const float* __restrict__ gleak,
    const float* __restrict__ cm, const float* __restrict__ W_fc,
    const float* __restrict__ b_fc, float* __restrict__ out)
{
    const int tid  = threadIdx.x;
    const int lane = tid & 63;
    const int wv   = tid >> 6;          // wave 0..7, owns hidden units [32*wv, 32*wv+32)
    const int c16  = lane & 15;
    const int kg   = lane >> 4;         // k-group (8 contiguous k per lane)
    const int row0 = blockIdx.x * 2;    // global batch rows row0, row0+1

    __shared__ __align__(16) unsigned short abuf[2][264];   // h_eff bf16
    __shared__ __align__(16) unsigned short xbuf[2][72];    // x_t bf16
    __shared__ __align__(16) unsigned short wxl[512][78];   // W_gd x-part bf16 (79.9 KB; keeps LDS > 80 KB total)
    __shared__ float hout[2][257];

    // ---- stage x-part of W_gd into LDS (bf16), zero h buffer ----
    for (int idx = tid; idx < 512 * 64; idx += 512) {
        int j = idx >> 6, i = idx & 63;
        wxl[j][i] = f2bf(W_gd[j * 320 + i]);
    }
    if (tid < 2 * 264) ((unsigned short*)abuf)[tid] = 0;

    // ---- recurrent weights (h-part of W_gd + W_tau) into registers, bf16 ----
    // tiles: 0:gate[uA] 1:gate[uB] 2:dyn[uA] 3:dyn[uB] 4:tau[uA] 5:tau[uB]
    const int uA = 32 * wv + c16;
    const int uB = uA + 16;
    bf16x8 Wr[6][8];
    {
        const int wrow[6] = { uA, uB, 256 + uA, 256 + uB, uA, uB };
        #pragma unroll
        for (int t = 0; t < 6; ++t) {
            const float* src = (t < 4) ? (W_gd + wrow[t] * 320 + 64)
                                       : (W_tau + wrow[t] * 256);
            #pragma unroll
            for (int s = 0; s < 8; ++s) {
                const float4* p = (const float4*)(src + s * 32 + kg * 8);
                float4 a = p[0], b = p[1];
                bf16x8 v;
                v[0] = (short)f2bf(a.x); v[1] = (short)f2bf(a.y);
                v[2] = (short)f2bf(a.z); v[3] = (short)f2bf(a.w);
                v[4] = (short)f2bf(b.x); v[5] = (short)f2bf(b.y);
                v[6] = (short)f2bf(b.z); v[7] = (short)f2bf(b.w);
                Wr[t][s] = v;
            }
        }
    }

    // per-lane constants (meaningful for lane<16; others compute discarded garbage)
    const float btau0 = b_tau[uA], btau1 = b_tau[uB];
    const float cden0 = __logf(1.f + __expf(cm[uA])) + __logf(1.f + __expf(gleak[uA])) + 1e-6f;
    const float cden1 = __logf(1.f + __expf(cm[uB])) + __logf(1.f + __expf(gleak[uB])) + 1e-6f;
    float bgd[4] = { b_gd[uA], b_gd[uB], b_gd[256 + uA], b_gd[256 + uB] };

    // A-operand LDS pointers; pad rows (c16>=2) broadcast-read row 0 (harmless:
    // MFMA output row r depends only on A row r; rows >=2 are never consumed)
    const int rsel = (c16 < 2) ? c16 : 0;
    const unsigned short* aptr = &abuf[rsel][kg * 8];
    const unsigned short* xptr = &xbuf[rsel][kg * 8];

    // RK state, fragment layout: lane<16 holds rows 0,1 (regs 0,1), col = lane
    float hv[2][2] = {{0.f, 0.f}, {0.f, 0.f}};
    f16x2 zh; zh[0] = (_Float16)0.f; zh[1] = (_Float16)0.f;
    f16x2 kk1[2] = { zh, zh }, kk2[2] = { zh, zh }, kk3[2] = { zh, zh };

    __syncthreads();

    #pragma unroll 1
    for (int ts = 0; ts < 128; ++ts) {
        // ---- stage x_t ----
        if (tid < 128) {
            int r = tid >> 6, i = tid & 63;
            xbuf[r][i] = f2bf(x[((row0 + r) * 128 + ts) * 64 + i]);
        }
        __syncthreads();

        // ---- x-part GEMM (once per step, reused by all 4 RK stages) ----
        f32x4 gx[4];
        #pragma unroll
        for (int t = 0; t < 4; ++t) gx[t] = (f32x4){0.f, 0.f, 0.f, 0.f};
        {
            const int xrow[4] = { uA, uB, 256 + uA, 256 + uB };
            #pragma unroll
            for (int s = 0; s < 2; ++s) {
                bf16x8 ax = *(const bf16x8*)(xptr + s * 32);
                #pragma unroll
                for (int t = 0; t < 4; ++t) {
                    bf16x8 bx = *(const bf16x8*)(&wxl[xrow[t]][kg * 8 + s * 32]);
                    gx[t] = MFMA(ax, bx, gx[t]);
                }
            }
        }
        f16x2 gdx[4];
        #pragma unroll
        for (int t = 0; t < 4; ++t) {
            gdx[t][0] = (_Float16)(gx[t][0] + bgd[t]);
            gdx[t][1] = (_Float16)(gx[t][1] + bgd[t]);
        }

        // ---- 4 RK stages (3/8-rule) ----
        #pragma unroll
        for (int stg = 0; stg < 4; ++stg) {
            // tau matmul first (releases its accs before gate/dyn)
            f32x4 aT0 = {0.f, 0.f, 0.f, 0.f}, aT1 = {0.f, 0.f, 0.f, 0.f};
            #pragma unroll
            for (int s = 0; s < 8; ++s) {
                bf16x8 A = *(const bf16x8*)(aptr + s * 32);
                aT0 = MFMA(A, Wr[4][s], aT0);
                aT1 = MFMA(A, Wr[5][s], aT1);
            }
            float den[2][2];
            den[0][0] = __logf(1.f + __expf(aT0[0] + btau0)) + cden0;
            den[0][1] = __logf(1.f + __expf(aT0[1] + btau0)) + cden0;
            den[1][0] = __logf(1.f + __expf(aT1[0] + btau1)) + cden1;
            den[1][1] = __logf(1.f + __expf(aT1[1] + btau1)) + cden1;

            // gate/dyn matmul
            f32x4 g[4];
            #pragma unroll
            for (int t = 0; t < 4; ++t) g[t] = (f32x4){0.f, 0.f, 0.f, 0.f};
            #pragma unroll
            for (int s = 0; s < 8; ++s) {
                bf16x8 A = *(const bf16x8*)(aptr + s * 32);
                #pragma unroll
                for (int t = 0; t < 4; ++t) g[t] = MFMA(A, Wr[t][s], g[t]);
            }
            __syncthreads();   // all abuf reads of this stage are done

            // elementwise dhdt + RK bookkeeping (4 real slots/lane: 2 units x 2 rows)
            #pragma unroll
            for (int ti = 0; ti < 2; ++ti) {
                #pragma unroll
                for (int r = 0; r < 2; ++r) {
                    float gate = g[ti][r]     + (float)gdx[ti][r];
                    float dyn  = g[2 + ti][r] + (float)gdx[2 + ti][r];
                    float sig = __fdividef(1.f, 1.f + __expf(-gate));
                    float th  = 1.f - __fdividef(2.f, __expf(2.f * dyn) + 1.f);
                    float k1v = (float)kk1[ti][r];
                    float k2v = (float)kk2[ti][r];
                    float k3v = (float)kk3[ti][r];
                    float h0 = hv[ti][r];
                    float ec;                      // dhdt argument of this stage
                    if      (stg == 0) ec = h0;
                    else if (stg == 1) ec = h0 + k1v * (1.f / 3.f);
                    else if (stg == 2) ec = h0 - k1v * (1.f / 3.f) + k2v;
                    else               ec = h0 + k1v - k2v + k3v;
                    float kv = __fdividef(sig * th - ec, den[ti][r]);
                    float en;
                    if (stg == 0)      { kk1[ti][r] = (_Float16)kv; en = h0 + kv * (1.f / 3.f); }
                    else if (stg == 1) { kk2[ti][r] = (_Float16)kv; en = h0 - k1v * (1.f / 3.f) + kv; }
                    else if (stg == 2) { kk3[ti][r] = (_Float16)kv; en = h0 + k1v - k2v + kv; }
                    else               { en = h0 + 0.125f * (k1v + 3.f * (k2v + k3v) + kv); hv[ti][r] = en; }
                    if (lane < 16) {
                        int u = (ti == 0) ? uA : uB;
                        abuf[r][u] = f2bf(en);
                    }
                }
            }
            __syncthreads();   // writes visible before next stage's reads
        }
    }

    // ---- epilogue: out = h @ W_fc^T + b_fc ----
    if (lane < 16) {
        hout[0][uA] = hv[0][0]; hout[1][uA] = hv[0][1];
        hout[0][uB] = hv[1][0]; hout[1][uB] = hv[1][1];
    }
    __syncthreads();
    if (tid < 20) {
        int r = tid / 10, c = tid % 10;
        float acc = b_fc[c];
        for (int k = 0; k < 256; ++k) acc = fmaf(hout[r][k], W_fc[c * 256 + k], acc);
        out[(row0 + r) * 10 + c] = acc;
    }
}

extern "C" void kernel_launch(void* const* d_in, const int* in_sizes, int n_in,
                              void* d_out, int out_size, void* d_ws, size_t ws_size,
                              hipStream_t stream) {
    (void)in_sizes; (void)n_in; (void)out_size; (void)d_ws; (void)ws_size;
    ltc_kernel<<<256, 512, 0, stream>>>(
        (const float*)d_in[0], (const float*)d_in[1], (const float*)d_in[2],
        (const float*)d_in[3], (const float*)d_in[4], (const float*)d_in[5],
        (const float*)d_in[6], (const float*)d_in[7], (const float*)d_in[8],
        (float*)d_out);
}

// Round 6
// 1773.222 us; speedup vs baseline: 1.0343x; 1.0343x over previous
//
#include <hip/hip_runtime.h>

typedef __attribute__((ext_vector_type(8))) short bf16x8;
typedef __attribute__((ext_vector_type(4))) float f32x4;
typedef __attribute__((ext_vector_type(2))) _Float16 f16x2;

#define MFMA(a, b, c) __builtin_amdgcn_mfma_f32_16x16x32_bf16((a), (b), (c), 0, 0, 0)

__device__ __forceinline__ unsigned short f2bf(float f) {
    unsigned int u = __builtin_bit_cast(unsigned int, f);
    return (unsigned short)((u + 0x7FFFu + ((u >> 16) & 1u)) >> 16);  // RNE
}

// B=512, S=128, I=64, H=256, C=10
// 256 blocks (2 batch rows each) x 512 threads (8 waves), 1 block/CU.
//
// Register-budget model (fits ALL of R1-R5 + learn_hip m97): the backend
// budgets VGPRs for `min_blocks` co-resident blocks, where min_blocks is the
// CUDA-style 2nd __launch_bounds__ arg, DEFAULT 2:
//   R1 (512,2):   2 blk x 8 wv / 4 SIMD = 4 w/EU -> 512/4 = 128   (observed)
//   R3 (1024,-):  2 blk x 16 / 4        = 8 w/EU -> 64            (observed)
//   m97 (256,-):  2 blk x 4  / 4        = 2 w/EU -> 256           (observed 228)
// amdgpu_waves_per_eu / amdgpu_num_vgpr were both ignored (R2/R4/R5).
// Therefore: __launch_bounds__(512, 1) -> 1 blk x 8 wv / 4 = 2 w/EU -> 256
// VGPR budget; the 192-VGPR weight set + ~50 overhead fits without spill.
__global__ __launch_bounds__(512, 1)
void ltc_kernel(
    const float* __restrict__ x, const float* __restrict__ W_gd,
    const float* __restrict__ b_gd, const float* __restrict__ W_tau,
    const float* __restrict__ b_tau, const float* __restrict__ gleak,
    const float* __restrict__ cm, const float* __restrict__ W_fc,
    const float* __restrict__ b_fc, float* __restrict__ out)
{
    const int tid  = threadIdx.x;
    const int lane = tid & 63;
    const int wv   = tid >> 6;          // wave 0..7, owns hidden units [32*wv, 32*wv+32)
    const int c16  = lane & 15;
    const int kg   = lane >> 4;         // k-group (8 contiguous k per lane)
    const int row0 = blockIdx.x * 2;    // global batch rows row0, row0+1

    __shared__ __align__(16) unsigned short abuf[2][264];   // h_eff bf16
    __shared__ __align__(16) unsigned short xbuf[2][72];    // x_t bf16
    __shared__ __align__(16) unsigned short wxl[512][78];   // W_gd x-part bf16 (79.9 KB)
    __shared__ float hout[2][257];

    // ---- stage x-part of W_gd into LDS (bf16), zero h buffer ----
    for (int idx = tid; idx < 512 * 64; idx += 512) {
        int j = idx >> 6, i = idx & 63;
        wxl[j][i] = f2bf(W_gd[j * 320 + i]);
    }
    if (tid < 2 * 264) ((unsigned short*)abuf)[tid] = 0;

    // ---- recurrent weights (h-part of W_gd + W_tau) into registers, bf16 ----
    // tiles: 0:gate[uA] 1:gate[uB] 2:dyn[uA] 3:dyn[uB] 4:tau[uA] 5:tau[uB]
    const int uA = 32 * wv + c16;
    const int uB = uA + 16;
    bf16x8 Wr[6][8];
    {
        const int wrow[6] = { uA, uB, 256 + uA, 256 + uB, uA, uB };
        #pragma unroll
        for (int t = 0; t < 6; ++t) {
            const float* src = (t < 4) ? (W_gd + wrow[t] * 320 + 64)
                                       : (W_tau + wrow[t] * 256);
            #pragma unroll
            for (int s = 0; s < 8; ++s) {
                const float4* p = (const float4*)(src + s * 32 + kg * 8);
                float4 a = p[0], b = p[1];
                bf16x8 v;
                v[0] = (short)f2bf(a.x); v[1] = (short)f2bf(a.y);
                v[2] = (short)f2bf(a.z); v[3] = (short)f2bf(a.w);
                v[4] = (short)f2bf(b.x); v[5] = (short)f2bf(b.y);
                v[6] = (short)f2bf(b.z); v[7] = (short)f2bf(b.w);
                Wr[t][s] = v;
            }
        }
    }

    // per-lane constants (meaningful for lane<16; others compute discarded garbage)
    const float btau0 = b_tau[uA], btau1 = b_tau[uB];
    const float cden0 = __logf(1.f + __expf(cm[uA])) + __logf(1.f + __expf(gleak[uA])) + 1e-6f;
    const float cden1 = __logf(1.f + __expf(cm[uB])) + __logf(1.f + __expf(gleak[uB])) + 1e-6f;
    float bgd[4] = { b_gd[uA], b_gd[uB], b_gd[256 + uA], b_gd[256 + uB] };

    // A-operand LDS pointers; pad rows (c16>=2) broadcast-read row 0 (harmless:
    // MFMA output row r depends only on A row r; rows >=2 are never consumed)
    const int rsel = (c16 < 2) ? c16 : 0;
    const unsigned short* aptr = &abuf[rsel][kg * 8];
    const unsigned short* xptr = &xbuf[rsel][kg * 8];

    // RK state, fragment layout: lane<16 holds rows 0,1 (regs 0,1), col = lane
    float hv[2][2] = {{0.f, 0.f}, {0.f, 0.f}};
    f16x2 zh; zh[0] = (_Float16)0.f; zh[1] = (_Float16)0.f;
    f16x2 kk1[2] = { zh, zh }, kk2[2] = { zh, zh }, kk3[2] = { zh, zh };

    __syncthreads();

    #pragma unroll 1
    for (int ts = 0; ts < 128; ++ts) {
        // ---- stage x_t ----
        if (tid < 128) {
            int r = tid >> 6, i = tid & 63;
            xbuf[r][i] = f2bf(x[((row0 + r) * 128 + ts) * 64 + i]);
        }
        __syncthreads();

        // ---- x-part GEMM (once per step, reused by all 4 RK stages) ----
        f32x4 gx[4];
        #pragma unroll
        for (int t = 0; t < 4; ++t) gx[t] = (f32x4){0.f, 0.f, 0.f, 0.f};
        {
            const int xrow[4] = { uA, uB, 256 + uA, 256 + uB };
            #pragma unroll
            for (int s = 0; s < 2; ++s) {
                bf16x8 ax = *(const bf16x8*)(xptr + s * 32);
                #pragma unroll
                for (int t = 0; t < 4; ++t) {
                    bf16x8 bx = *(const bf16x8*)(&wxl[xrow[t]][kg * 8 + s * 32]);
                    gx[t] = MFMA(ax, bx, gx[t]);
                }
            }
        }
        f16x2 gdx[4];
        #pragma unroll
        for (int t = 0; t < 4; ++t) {
            gdx[t][0] = (_Float16)(gx[t][0] + bgd[t]);
            gdx[t][1] = (_Float16)(gx[t][1] + bgd[t]);
        }

        // ---- 4 RK stages (3/8-rule) ----
        #pragma unroll
        for (int stg = 0; stg < 4; ++stg) {
            // tau matmul first (releases its accs before gate/dyn)
            f32x4 aT0 = {0.f, 0.f, 0.f, 0.f}, aT1 = {0.f, 0.f, 0.f, 0.f};
            #pragma unroll
            for (int s = 0; s < 8; ++s) {
                bf16x8 A = *(const bf16x8*)(aptr + s * 32);
                aT0 = MFMA(A, Wr[4][s], aT0);
                aT1 = MFMA(A, Wr[5][s], aT1);
            }
            float den[2][2];
            den[0][0] = __logf(1.f + __expf(aT0[0] + btau0)) + cden0;
            den[0][1] = __logf(1.f + __expf(aT0[1] + btau0)) + cden0;
            den[1][0] = __logf(1.f + __expf(aT1[0] + btau1)) + cden1;
            den[1][1] = __logf(1.f + __expf(aT1[1] + btau1)) + cden1;

            // gate/dyn matmul
            f32x4 g[4];
            #pragma unroll
            for (int t = 0; t < 4; ++t) g[t] = (f32x4){0.f, 0.f, 0.f, 0.f};
            #pragma unroll
            for (int s = 0; s < 8; ++s) {
                bf16x8 A = *(const bf16x8*)(aptr + s * 32);
                #pragma unroll
                for (int t = 0; t < 4; ++t) g[t] = MFMA(A, Wr[t][s], g[t]);
            }
            __syncthreads();   // all abuf reads of this stage are done

            // elementwise dhdt + RK bookkeeping (4 real slots/lane: 2 units x 2 rows)
            #pragma unroll
            for (int ti = 0; ti < 2; ++ti) {
                #pragma unroll
                for (int r = 0; r < 2; ++r) {
                    float gate = g[ti][r]     + (float)gdx[ti][r];
                    float dyn  = g[2 + ti][r] + (float)gdx[2 + ti][r];
                    float sig = __fdividef(1.f, 1.f + __expf(-gate));
                    float th  = 1.f - __fdividef(2.f, __expf(2.f * dyn) + 1.f);
                    float k1v = (float)kk1[ti][r];
                    float k2v = (float)kk2[ti][r];
                    float k3v = (float)kk3[ti][r];
                    float h0 = hv[ti][r];
                    float ec;                      // dhdt argument of this stage
                    if      (stg == 0) ec = h0;
                    else if (stg == 1) ec = h0 + k1v * (1.f / 3.f);
                    else if (stg == 2) ec = h0 - k1v * (1.f / 3.f) + k2v;
                    else               ec = h0 + k1v - k2v + k3v;
                    float kv = __fdividef(sig * th - ec, den[ti][r]);
                    float en;
                    if (stg == 0)      { kk1[ti][r] = (_Float16)kv; en = h0 + kv * (1.f / 3.f); }
                    else if (stg == 1) { kk2[ti][r] = (_Float16)kv; en = h0 - k1v * (1.f / 3.f) + kv; }
                    else if (stg == 2) { kk3[ti][r] = (_Float16)kv; en = h0 + k1v - k2v + kv; }
                    else               { en = h0 + 0.125f * (k1v + 3.f * (k2v + k3v) + kv); hv[ti][r] = en; }
                    if (lane < 16) {
                        int u = (ti == 0) ? uA : uB;
                        abuf[r][u] = f2bf(en);
                    }
                }
            }
            __syncthreads();   // writes visible before next stage's reads
        }
    }

    // ---- epilogue: out = h @ W_fc^T + b_fc ----
    if (lane < 16) {
        hout[0][uA] = hv[0][0]; hout[1][uA] = hv[0][1];
        hout[0][uB] = hv[1][0]; hout[1][uB] = hv[1][1];
    }
    __syncthreads();
    if (tid < 20) {
        int r = tid / 10, c = tid % 10;
        float acc = b_fc[c];
        for (int k = 0; k < 256; ++k) acc = fmaf(hout[r][k], W_fc[c * 256 + k], acc);
        out[(row0 + r) * 10 + c] = acc;
    }
}

extern "C" void kernel_launch(void* const* d_in, const int* in_sizes, int n_in,
                              void* d_out, int out_size, void* d_ws, size_t ws_size,
                              hipStream_t stream) {
    (void)in_sizes; (void)n_in; (void)out_size; (void)d_ws; (void)ws_size;
    ltc_kernel<<<256, 512, 0, stream>>>(
        (const float*)d_in[0], (const float*)d_in[1], (const float*)d_in[2],
        (const float*)d_in[3], (const float*)d_in[4], (const float*)d_in[5],
        (const float*)d_in[6], (const float*)d_in[7], (const float*)d_in[8],
        (float*)d_out);
}

// Round 7
// 1130.242 us; speedup vs baseline: 1.6227x; 1.5689x over previous
//
#include <hip/hip_runtime.h>

typedef __attribute__((ext_vector_type(8))) short bf16x8;
typedef __attribute__((ext_vector_type(4))) float f32x4;
typedef __attribute__((ext_vector_type(2))) _Float16 f16x2;

#define MFMA(a, b, c) __builtin_amdgcn_mfma_f32_16x16x32_bf16((a), (b), (c), 0, 0, 0)

__device__ __forceinline__ unsigned short f2bf(float f) {
    unsigned int u = __builtin_bit_cast(unsigned int, f);
    return (unsigned short)((u + 0x7FFFu + ((u >> 16) & 1u)) >> 16);  // RNE
}

// Prepack to bf16 in ws: dyn h-weights [256 u][256 k] at ws[0..65535],
// W_x [512 out][64 k] at ws[65536..98303]. (192 KB of d_ws)
__global__ __launch_bounds__(256) void prepack_kernel(const float* __restrict__ W_gd,
                                                      unsigned short* __restrict__ ws) {
    int i = blockIdx.x * 256 + threadIdx.x;                     // 0..65535
    ws[i] = f2bf(W_gd[(256 + (i >> 8)) * 320 + 64 + (i & 255)]);
    if (i < 32768) ws[65536 + i] = f2bf(W_gd[(i >> 6) * 320 + (i & 63)]);
}

// B=512, S=128, I=64, H=256, C=10
// 256 blocks (2 batch rows) x 512 threads (8 waves), 1 block/CU.
//
// R1-R6 forensics: VGPR budget is hard-pinned at 65536/blockDim (128 @ 512T)
// by the toolchain; no attribute moves it. Full weight residency (384 KB) is
// structurally impossible, and spills are the worst tier (per-lane private ->
// ~393 KB/CU/stage of L2 traffic = the 1.8 ms plateau). So: PLANNED partition.
//   regs (64/lane): gate weights (128 KB/CU)
//   LDS  (147 KB):  tau full 128 KB (XOR-swizzled) + dyn chunk0 16 KB + bufs
//   L2 stream:      dyn chunks 1..7 (112 KB/CU/stage) as prepacked bf16 from
//                   ws -- SHARED bytes (L2 broadcast), not per-lane spills.
__global__ __launch_bounds__(512, 1)
void ltc_kernel(
    const float* __restrict__ x, const float* __restrict__ W_gd,
    const float* __restrict__ b_gd, const float* __restrict__ W_tau,
    const float* __restrict__ b_tau, const float* __restrict__ gleak,
    const float* __restrict__ cm, const float* __restrict__ W_fc,
    const float* __restrict__ b_fc, const unsigned short* __restrict__ ws,
    float* __restrict__ out)
{
    const int tid  = threadIdx.x;
    const int lane = tid & 63;
    const int wv   = tid >> 6;          // wave 0..7, owns hidden units [32*wv, 32*wv+32)
    const int c16  = lane & 15;
    const int kg   = lane >> 4;         // k-group (8 contiguous k per lane)
    const int row0 = blockIdx.x * 2;    // global batch rows row0, row0+1

    __shared__ __align__(16) unsigned short tauL[65536];    // tau weights, swizzled (128 KB)
    __shared__ __align__(16) unsigned short dynL[8192];     // dyn K-chunk 0, swizzled (16 KB)
    __shared__ __align__(16) unsigned short abuf[2][264];   // h_eff bf16
    __shared__ __align__(16) unsigned short xbuf[2][72];    // x_t bf16
    __shared__ float hout[2][257];

    const int uA = 32 * wv + c16;
    const int uB = uA + 16;
    const int swzA = (uA & 7) << 3;     // tau u16-index XOR swizzle (same for uB: +16 keeps low 3 bits)
    const int swzD = (uA & 3) << 3;     // dynL swizzle

    // ---- LDS fills (once) ----
    for (int i = tid; i < 65536; i += 512) {                 // tau 256x256
        int u = i >> 8, k = i & 255;
        tauL[u * 256 + (k ^ ((u & 7) << 3))] = f2bf(W_tau[u * 256 + k]);
    }
    for (int i = tid; i < 8192; i += 512) {                  // dyn chunk 0 (k=0..31)
        int u = i >> 5, k = i & 31;
        dynL[u * 32 + (k ^ ((u & 3) << 3))] = f2bf(W_gd[(256 + u) * 320 + 64 + k]);
    }
    for (int i = tid; i < 2 * 264; i += 512) ((unsigned short*)abuf)[i] = 0;  // loop, not if (R5 latent bug)

    // ---- gate weights into registers (2 tiles x 8 K-chunks = 64 VGPR) ----
    bf16x8 Wg[2][8];
    {
        const int wrow[2] = { uA, uB };
        #pragma unroll
        for (int t = 0; t < 2; ++t) {
            const float* src = W_gd + wrow[t] * 320 + 64;
            #pragma unroll
            for (int s = 0; s < 8; ++s) {
                const float4* p = (const float4*)(src + s * 32 + kg * 8);
                float4 a = p[0], b = p[1];
                bf16x8 v;
                v[0] = (short)f2bf(a.x); v[1] = (short)f2bf(a.y);
                v[2] = (short)f2bf(a.z); v[3] = (short)f2bf(a.w);
                v[4] = (short)f2bf(b.x); v[5] = (short)f2bf(b.y);
                v[6] = (short)f2bf(b.z); v[7] = (short)f2bf(b.w);
                Wg[t][s] = v;
            }
        }
    }

    // per-lane constants
    const float btau0 = b_tau[uA], btau1 = b_tau[uB];
    const float cden0 = __logf(1.f + __expf(cm[uA])) + __logf(1.f + __expf(gleak[uA])) + 1e-6f;
    const float cden1 = __logf(1.f + __expf(cm[uB])) + __logf(1.f + __expf(gleak[uB])) + 1e-6f;
    float bgd[4] = { b_gd[uA], b_gd[uB], b_gd[256 + uA], b_gd[256 + uB] };

    // A-operand LDS pointers; pad rows (c16>=2) broadcast-read row 0
    const int rsel = (c16 < 2) ? c16 : 0;
    const unsigned short* aptr = &abuf[rsel][kg * 8];
    const unsigned short* xptr = &xbuf[rsel][kg * 8];
    const unsigned short* wsx  = ws + 65536;

    // RK state (lane<16 holds rows 0,1)
    float hv[2][2] = {{0.f, 0.f}, {0.f, 0.f}};
    f16x2 zh; zh[0] = (_Float16)0.f; zh[1] = (_Float16)0.f;
    f16x2 kk1[2] = { zh, zh }, kk2[2] = { zh, zh }, kk3[2] = { zh, zh };

    __syncthreads();

    #pragma unroll 1
    for (int ts = 0; ts < 128; ++ts) {
        // ---- stage x_t ----
        if (tid < 128) {
            int r = tid >> 6, i = tid & 63;
            xbuf[r][i] = f2bf(x[((row0 + r) * 128 + ts) * 64 + i]);
        }
        __syncthreads();

        // ---- x-part GEMM (once per step, from prepacked bf16 W_x) ----
        f32x4 gx[4];
        #pragma unroll
        for (int t = 0; t < 4; ++t) gx[t] = (f32x4){0.f, 0.f, 0.f, 0.f};
        {
            const int xo[4] = { uA, uB, 256 + uA, 256 + uB };
            #pragma unroll
            for (int s = 0; s < 2; ++s) {
                bf16x8 ax = *(const bf16x8*)(xptr + s * 32);
                #pragma unroll
                for (int t = 0; t < 4; ++t) {
                    bf16x8 bx = *(const bf16x8*)(wsx + xo[t] * 64 + s * 32 + kg * 8);
                    gx[t] = MFMA(ax, bx, gx[t]);
                }
            }
        }
        f16x2 gdx[4];
        #pragma unroll
        for (int t = 0; t < 4; ++t) {
            gdx[t][0] = (_Float16)(gx[t][0] + bgd[t]);
            gdx[t][1] = (_Float16)(gx[t][1] + bgd[t]);
        }

        // ---- 4 RK stages ----
        #pragma unroll
        for (int stg = 0; stg < 4; ++stg) {
            // resident matmuls: tau (LDS, swizzled) + gate (regs), one K-sweep
            f32x4 T0 = {0.f,0.f,0.f,0.f}, T1 = {0.f,0.f,0.f,0.f};
            f32x4 G0 = {0.f,0.f,0.f,0.f}, G1 = {0.f,0.f,0.f,0.f};
            #pragma unroll
            for (int s = 0; s < 8; ++s) {
                bf16x8 A  = *(const bf16x8*)(aptr + s * 32);
                bf16x8 tA = *(const bf16x8*)(tauL + uA * 256 + ((s * 32 + kg * 8) ^ swzA));
                bf16x8 tB = *(const bf16x8*)(tauL + uB * 256 + ((s * 32 + kg * 8) ^ swzA));
                T0 = MFMA(A, tA, T0);
                T1 = MFMA(A, tB, T1);
                G0 = MFMA(A, Wg[0][s], G0);
                G1 = MFMA(A, Wg[1][s], G1);
            }
            float den[2][2];
            den[0][0] = __logf(1.f + __expf(T0[0] + btau0)) + cden0;
            den[0][1] = __logf(1.f + __expf(T0[1] + btau0)) + cden0;
            den[1][0] = __logf(1.f + __expf(T1[0] + btau1)) + cden1;
            den[1][1] = __logf(1.f + __expf(T1[1] + btau1)) + cden1;

            // dyn uA: chunk0 from LDS, chunks 1..7 streamed from ws (L2)
            f32x4 D0 = {0.f,0.f,0.f,0.f};
            {
                bf16x8 A0 = *(const bf16x8*)(aptr);
                bf16x8 dA = *(const bf16x8*)(dynL + uA * 32 + ((kg * 8) ^ swzD));
                D0 = MFMA(A0, dA, D0);
                #pragma unroll
                for (int s = 1; s < 8; ++s) {
                    bf16x8 A = *(const bf16x8*)(aptr + s * 32);
                    bf16x8 B = *(const bf16x8*)(ws + uA * 256 + s * 32 + kg * 8);
                    D0 = MFMA(A, B, D0);
                }
            }
            // dyn uB
            f32x4 D1 = {0.f,0.f,0.f,0.f};
            {
                bf16x8 A0 = *(const bf16x8*)(aptr);
                bf16x8 dB = *(const bf16x8*)(dynL + uB * 32 + ((kg * 8) ^ swzD));
                D1 = MFMA(A0, dB, D1);
                #pragma unroll
                for (int s = 1; s < 8; ++s) {
                    bf16x8 A = *(const bf16x8*)(aptr + s * 32);
                    bf16x8 B = *(const bf16x8*)(ws + uB * 256 + s * 32 + kg * 8);
                    D1 = MFMA(A, B, D1);
                }
            }
            __syncthreads();   // all abuf reads of this stage done

            // elementwise dhdt + RK bookkeeping (ti=0 -> uA, ti=1 -> uB)
            #pragma unroll
            for (int ti = 0; ti < 2; ++ti) {
                #pragma unroll
                for (int r = 0; r < 2; ++r) {
                    float gate = (ti == 0 ? G0[r] : G1[r]) + (float)gdx[ti][r];
                    float dyn  = (ti == 0 ? D0[r] : D1[r]) + (float)gdx[2 + ti][r];
                    float sig = __fdividef(1.f, 1.f + __expf(-gate));
                    float th  = 1.f - __fdividef(2.f, __expf(2.f * dyn) + 1.f);
                    float k1v = (float)kk1[ti][r];
                    float k2v = (float)kk2[ti][r];
                    float k3v = (float)kk3[ti][r];
                    float h0 = hv[ti][r];
                    float ec;
                    if      (stg == 0) ec = h0;
                    else if (stg == 1) ec = h0 + k1v * (1.f / 3.f);
                    else if (stg == 2) ec = h0 - k1v * (1.f / 3.f) + k2v;
                    else               ec = h0 + k1v - k2v + k3v;
                    float kv = __fdividef(sig * th - ec, den[ti][r]);
                    float en;
                    if (stg == 0)      { kk1[ti][r] = (_Float16)kv; en = h0 + kv * (1.f / 3.f); }
                    else if (stg == 1) { kk2[ti][r] = (_Float16)kv; en = h0 - k1v * (1.f / 3.f) + kv; }
                    else if (stg == 2) { kk3[ti][r] = (_Float16)kv; en = h0 + k1v - k2v + kv; }
                    else               { en = h0 + 0.125f * (k1v + 3.f * (k2v + k3v) + kv); hv[ti][r] = en; }
                    if (lane < 16) {
                        int u = (ti == 0) ? uA : uB;
                        abuf[r][u] = f2bf(en);
                    }
                }
            }
            __syncthreads();   // writes visible before next stage
        }
    }

    // ---- epilogue: out = h @ W_fc^T + b_fc ----
    if (lane < 16) {
        hout[0][uA] = hv[0][0]; hout[1][uA] = hv[0][1];
        hout[0][uB] = hv[1][0]; hout[1][uB] = hv[1][1];
    }
    __syncthreads();
    if (tid < 20) {
        int r = tid / 10, c = tid % 10;
        float acc = b_fc[c];
        for (int k = 0; k < 256; ++k) acc = fmaf(hout[r][k], W_fc[c * 256 + k], acc);
        out[(row0 + r) * 10 + c] = acc;
    }
}

extern "C" void kernel_launch(void* const* d_in, const int* in_sizes, int n_in,
                              void* d_out, int out_size, void* d_ws, size_t ws_size,
                              hipStream_t stream) {
    (void)in_sizes; (void)n_in; (void)out_size; (void)ws_size;
    unsigned short* ws16 = (unsigned short*)d_ws;
    prepack_kernel<<<256, 256, 0, stream>>>((const float*)d_in[1], ws16);
    ltc_kernel<<<256, 512, 0, stream>>>(
        (const float*)d_in[0], (const float*)d_in[1], (const float*)d_in[2],
        (const float*)d_in[3], (const float*)d_in[4], (const float*)d_in[5],
        (const float*)d_in[6], (const float*)d_in[7], (const float*)d_in[8],
        ws16, (float*)d_out);
}

// Round 8
// 1019.453 us; speedup vs baseline: 1.7990x; 1.1087x over previous
//
#include <hip/hip_runtime.h>

typedef __attribute__((ext_vector_type(8))) short bf16x8;
typedef __attribute__((ext_vector_type(4))) float f32x4;
typedef __attribute__((ext_vector_type(2))) _Float16 f16x2;

#define MFMA(a, b, c) __builtin_amdgcn_mfma_f32_16x16x32_bf16((a), (b), (c), 0, 0, 0)

__device__ __forceinline__ unsigned short f2bf(float f) {
    unsigned int u = __builtin_bit_cast(unsigned int, f);
    return (unsigned short)((u + 0x7FFFu + ((u >> 16) & 1u)) >> 16);  // RNE
}
__device__ __forceinline__ float softplusf(float v) {
    return __logf(1.f + __expf(v));
}

// Prepack to bf16 in ws: dyn h-weights [256 u][256 k] at ws[0..65535],
// W_x [512 out][64 k] at ws[65536..98303]. (192 KB of d_ws)
__global__ __launch_bounds__(256) void prepack_kernel(const float* __restrict__ W_gd,
                                                      unsigned short* __restrict__ ws) {
    int i = blockIdx.x * 256 + threadIdx.x;                     // 0..65535
    ws[i] = f2bf(W_gd[(256 + (i >> 8)) * 320 + 64 + (i & 255)]);
    if (i < 32768) ws[65536 + i] = f2bf(W_gd[(i >> 6) * 320 + (i & 63)]);
}

// B=512, S=128, I=64, H=256, C=10
// 256 blocks (2 batch rows) x 512 threads (8 waves), 1 block/CU.
// Storage partition (VGPR budget hard-pinned at 128 = 65536/blockDim, R1-R6):
//   regs: gate weights (64) + 4-slot dyn-stream FIFO (16)
//   LDS:  tau full 128 KB (4-bit XOR swizzle = conflict-free) + dyn chunk0
//         16 KB + const tables + h/x bufs  (~151 KB -> 1 block/CU)
//   L2:   dyn chunks 1..7 (112 KB/CU/stage) streamed through the reg FIFO,
//         depth 4, refilled at every consume -> latency hidden under MFMA.
__global__ __launch_bounds__(512, 1)
void ltc_kernel(
    const float* __restrict__ x, const float* __restrict__ W_gd,
    const float* __restrict__ b_gd, const float* __restrict__ W_tau,
    const float* __restrict__ b_tau, const float* __restrict__ gleak,
    const float* __restrict__ cm, const float* __restrict__ W_fc,
    const float* __restrict__ b_fc, const unsigned short* __restrict__ ws,
    float* __restrict__ out)
{
    const int tid  = threadIdx.x;
    const int lane = tid & 63;
    const int wv   = tid >> 6;          // wave 0..7, owns hidden units [32*wv, 32*wv+32)
    const int c16  = lane & 15;
    const int kg   = lane >> 4;
    const int kg8  = kg * 8;
    const int row0 = blockIdx.x * 2;

    __shared__ __align__(16) unsigned short tauL[65536];    // tau, 4-bit swizzle (128 KB)
    __shared__ __align__(16) unsigned short dynL[8192];     // dyn K-chunk 0 (16 KB)
    __shared__ __align__(16) unsigned short abuf[2][264];   // h_eff bf16
    __shared__ __align__(16) unsigned short xbuf[2][72];    // x_t bf16
    __shared__ __align__(8)  float tcL[512];                // {b_tau, cden} per unit
    __shared__ float bgdL[512];
    __shared__ float hout[2][257];

    // ---- LDS fills (once) ----
    for (int i = tid; i < 65536; i += 512) {                 // tau, swizzled k ^= (u&15)<<3
        int u = i >> 8, k = i & 255;
        tauL[u * 256 + (k ^ ((u & 15) << 3))] = f2bf(W_tau[i]);
    }
    for (int i = tid; i < 8192; i += 512) {                  // dyn chunk 0 (k<32)
        int u = i >> 5, k = i & 31;
        dynL[u * 32 + (k ^ ((u & 3) << 3))] = f2bf(W_gd[(256 + u) * 320 + 64 + k]);
    }
    for (int i = tid; i < 2 * 264; i += 512) ((unsigned short*)abuf)[i] = 0;
    if (tid < 256) {
        tcL[2 * tid]     = b_tau[tid];
        tcL[2 * tid + 1] = softplusf(cm[tid]) + softplusf(gleak[tid]) + 1e-6f;
    }
    bgdL[tid] = b_gd[tid];

    const int uA = 32 * wv + c16;
    const int uB = uA + 16;
    const int tswz = c16 << 3;                               // tau swizzle (u&15 == c16 for uA,uB)
    const unsigned short* tAb = tauL + uA * 256;
    const unsigned short* tBb = tauL + uB * 256;
    const bf16x8* dA0p = (const bf16x8*)(dynL + uA * 32 + (kg8 ^ ((c16 & 3) << 3)));
    const bf16x8* dB0p = (const bf16x8*)(dynL + uB * 32 + (kg8 ^ ((c16 & 3) << 3)));
    const unsigned short* sA  = ws + uA * 256 + kg8;         // dyn stream bases (bf16 in ws)
    const unsigned short* sB  = ws + uB * 256 + kg8;
    const unsigned short* wsx = ws + 65536;

    // ---- gate weights into registers (64 VGPR) ----
    bf16x8 Wg[2][8];
    {
        const int wrow[2] = { uA, uB };
        #pragma unroll
        for (int t = 0; t < 2; ++t) {
            const float* src = W_gd + wrow[t] * 320 + 64;
            #pragma unroll
            for (int s = 0; s < 8; ++s) {
                const float4* p = (const float4*)(src + s * 32 + kg8);
                float4 a = p[0], b = p[1];
                bf16x8 v;
                v[0] = (short)f2bf(a.x); v[1] = (short)f2bf(a.y);
                v[2] = (short)f2bf(a.z); v[3] = (short)f2bf(a.w);
                v[4] = (short)f2bf(b.x); v[5] = (short)f2bf(b.y);
                v[6] = (short)f2bf(b.z); v[7] = (short)f2bf(b.w);
                Wg[t][s] = v;
            }
        }
    }

    const int rsel = (c16 < 2) ? c16 : 0;
    const unsigned short* aptr = &abuf[rsel][kg8];
    const unsigned short* xptr = &xbuf[rsel][kg8];

    float hv[2][2] = {{0.f, 0.f}, {0.f, 0.f}};
    f16x2 zh; zh[0] = (_Float16)0.f; zh[1] = (_Float16)0.f;
    f16x2 kk1[2] = { zh, zh }, kk2[2] = { zh, zh }, kk3[2] = { zh, zh };

    // ---- stream FIFO prologue: frags 0..3 (uA s=1..4) into slots 0..3 ----
    bf16x8 pipe[4];
    pipe[0] = *(const bf16x8*)(sA + 32);
    pipe[1] = *(const bf16x8*)(sA + 64);
    pipe[2] = *(const bf16x8*)(sA + 96);
    pipe[3] = *(const bf16x8*)(sA + 128);

    __syncthreads();

// elementwise dhdt + RK bookkeeping for one tile (ti = 0 -> uA, 1 -> uB)
#define ELEM(ti, G, D, den, en)                                                  \
    _Pragma("unroll")                                                            \
    for (int r = 0; r < 2; ++r) {                                                \
        float gate = G[r] + (float)gdx[ti][r];                                   \
        float dyn  = D[r] + (float)gdx[2 + ti][r];                               \
        float sig = __fdividef(1.f, 1.f + __expf(-gate));                        \
        float th  = 1.f - __fdividef(2.f, __expf(2.f * dyn) + 1.f);              \
        float k1v = (float)kk1[ti][r], k2v = (float)kk2[ti][r], k3v = (float)kk3[ti][r]; \
        float h0 = hv[ti][r];                                                    \
        float ec;                                                                \
        if      (stg == 0) ec = h0;                                              \
        else if (stg == 1) ec = h0 + k1v * (1.f / 3.f);                          \
        else if (stg == 2) ec = h0 - k1v * (1.f / 3.f) + k2v;                    \
        else               ec = h0 + k1v - k2v + k3v;                            \
        float kv = __fdividef(sig * th - ec, den[r]);                            \
        if (stg == 0)      { kk1[ti][r] = (_Float16)kv; en[r] = h0 + kv * (1.f / 3.f); } \
        else if (stg == 1) { kk2[ti][r] = (_Float16)kv; en[r] = h0 - k1v * (1.f / 3.f) + kv; } \
        else if (stg == 2) { kk3[ti][r] = (_Float16)kv; en[r] = h0 + k1v - k2v + kv; } \
        else               { en[r] = h0 + 0.125f * (k1v + 3.f * (k2v + k3v) + kv); hv[ti][r] = en[r]; } \
    }

    #pragma unroll 1
    for (int ts = 0; ts < 128; ++ts) {
        if (tid < 128) {
            int r = tid >> 6, i = tid & 63;
            xbuf[r][i] = f2bf(x[((row0 + r) * 128 + ts) * 64 + i]);
        }
        __syncthreads();

        // ---- x-part GEMM (once per step) ----
        f32x4 gx0 = {0,0,0,0}, gx1 = {0,0,0,0}, gx2 = {0,0,0,0}, gx3 = {0,0,0,0};
        #pragma unroll
        for (int s = 0; s < 2; ++s) {
            bf16x8 ax = *(const bf16x8*)(xptr + s * 32);
            gx0 = MFMA(ax, *(const bf16x8*)(wsx + uA * 64         + s * 32 + kg8), gx0);
            gx1 = MFMA(ax, *(const bf16x8*)(wsx + uB * 64         + s * 32 + kg8), gx1);
            gx2 = MFMA(ax, *(const bf16x8*)(wsx + (256 + uA) * 64 + s * 32 + kg8), gx2);
            gx3 = MFMA(ax, *(const bf16x8*)(wsx + (256 + uB) * 64 + s * 32 + kg8), gx3);
        }
        f16x2 gdx[4];
        {
            float bg0 = bgdL[uA], bg1 = bgdL[uB], bg2 = bgdL[256 + uA], bg3 = bgdL[256 + uB];
            gdx[0][0] = (_Float16)(gx0[0] + bg0); gdx[0][1] = (_Float16)(gx0[1] + bg0);
            gdx[1][0] = (_Float16)(gx1[0] + bg1); gdx[1][1] = (_Float16)(gx1[1] + bg1);
            gdx[2][0] = (_Float16)(gx2[0] + bg2); gdx[2][1] = (_Float16)(gx2[1] + bg2);
            gdx[3][0] = (_Float16)(gx3[0] + bg3); gdx[3][1] = (_Float16)(gx3[1] + bg3);
        }

        // ---- 4 RK stages (3/8-rule) ----
        #pragma unroll
        for (int stg = 0; stg < 4; ++stg) {
            // ---- uA sweep: tau(LDS) + gate(reg) + dyn(chunk0 LDS, 1..7 FIFO) ----
            f32x4 T0 = {0,0,0,0}, G0 = {0,0,0,0}, D0 = {0,0,0,0};
            {
                bf16x8 A = *(const bf16x8*)(aptr);
                T0 = MFMA(A, *(const bf16x8*)(tAb + (kg8 ^ tswz)), T0);
                G0 = MFMA(A, Wg[0][0], G0);
                D0 = MFMA(A, *dA0p, D0);
            }
            #pragma unroll
            for (int s = 1; s < 8; ++s) {
                bf16x8 A = *(const bf16x8*)(aptr + s * 32);
                T0 = MFMA(A, *(const bf16x8*)(tAb + ((s * 32 + kg8) ^ tswz)), T0);
                G0 = MFMA(A, Wg[0][s], G0);
                D0 = MFMA(A, pipe[(2 * stg + s - 1) & 3], D0);
                // refill same slot with frag f = s+3 (f<7 -> uA s=f+1, else uB s=f-6)
                if (s + 3 < 7) pipe[(2 * stg + s + 3) & 3] = *(const bf16x8*)(sA + (s + 4) * 32);
                else           pipe[(2 * stg + s + 3) & 3] = *(const bf16x8*)(sB + (s - 3) * 32);
            }
            float2 tc0 = *(const float2*)(tcL + 2 * uA);
            float den0[2];
            den0[0] = softplusf(T0[0] + tc0.x) + tc0.y;
            den0[1] = softplusf(T0[1] + tc0.x) + tc0.y;
            float en0[2];
            ELEM(0, G0, D0, den0, en0);

            // ---- uB sweep ----
            f32x4 T1 = {0,0,0,0}, G1 = {0,0,0,0}, D1 = {0,0,0,0};
            {
                bf16x8 A = *(const bf16x8*)(aptr);
                T1 = MFMA(A, *(const bf16x8*)(tBb + (kg8 ^ tswz)), T1);
                G1 = MFMA(A, Wg[1][0], G1);
                D1 = MFMA(A, *dB0p, D1);
            }
            #pragma unroll
            for (int s = 1; s < 8; ++s) {
                bf16x8 A = *(const bf16x8*)(aptr + s * 32);
                T1 = MFMA(A, *(const bf16x8*)(tBb + ((s * 32 + kg8) ^ tswz)), T1);
                G1 = MFMA(A, Wg[1][s], G1);
                D1 = MFMA(A, pipe[(2 * stg + 6 + s) & 3], D1);
                if (s <= 3) {   // frag 10+s of this stage (uB s+4)
                    pipe[(2 * stg + 10 + s) & 3] = *(const bf16x8*)(sB + (s + 4) * 32);
                } else {        // next stage's frag s-4 (uA s-3)
                    pipe[(2 * (stg + 1) + s - 4) & 3] = *(const bf16x8*)(sA + (s - 3) * 32);
                }
            }
            float2 tc1 = *(const float2*)(tcL + 2 * uB);
            float den1[2];
            den1[0] = softplusf(T1[0] + tc1.x) + tc1.y;
            den1[1] = softplusf(T1[1] + tc1.x) + tc1.y;
            float en1[2];
            ELEM(1, G1, D1, den1, en1);

            __syncthreads();   // all abuf reads of this stage done
            if (lane < 16) {
                abuf[0][uA] = f2bf(en0[0]); abuf[1][uA] = f2bf(en0[1]);
                abuf[0][uB] = f2bf(en1[0]); abuf[1][uB] = f2bf(en1[1]);
            }
            __syncthreads();   // writes visible before next stage
        }
    }
#undef ELEM

    // ---- epilogue: out = h @ W_fc^T + b_fc ----
    if (lane < 16) {
        hout[0][uA] = hv[0][0]; hout[1][uA] = hv[0][1];
        hout[0][uB] = hv[1][0]; hout[1][uB] = hv[1][1];
    }
    __syncthreads();
    if (tid < 20) {
        int r = tid / 10, c = tid % 10;
        float acc = b_fc[c];
        for (int k = 0; k < 256; ++k) acc = fmaf(hout[r][k], W_fc[c * 256 + k], acc);
        out[(row0 + r) * 10 + c] = acc;
    }
}

extern "C" void kernel_launch(void* const* d_in, const int* in_sizes, int n_in,
                              void* d_out, int out_size, void* d_ws, size_t ws_size,
                              hipStream_t stream) {
    (void)in_sizes; (void)n_in; (void)out_size; (void)ws_size;
    unsigned short* ws16 = (unsigned short*)d_ws;
    prepack_kernel<<<256, 256, 0, stream>>>((const float*)d_in[1], ws16);
    ltc_kernel<<<256, 512, 0, stream>>>(
        (const float*)d_in[0], (const float*)d_in[1], (const float*)d_in[2],
        (const float*)d_in[3], (const float*)d_in[4], (const float*)d_in[5],
        (const float*)d_in[6], (const float*)d_in[7], (const float*)d_in[8],
        ws16, (float*)d_out);
}

// Round 9
// 1013.294 us; speedup vs baseline: 1.8099x; 1.0061x over previous
//
#include <hip/hip_runtime.h>

typedef __attribute__((ext_vector_type(8))) short bf16x8;
typedef __attribute__((ext_vector_type(4))) float f32x4;
typedef __attribute__((ext_vector_type(2))) _Float16 f16x2;

#define MFMA(a, b, c) __builtin_amdgcn_mfma_f32_16x16x32_bf16((a), (b), (c), 0, 0, 0)

__device__ __forceinline__ unsigned short f2bf(float f) {
    unsigned int u = __builtin_bit_cast(unsigned int, f);
    return (unsigned short)((u + 0x7FFFu + ((u >> 16) & 1u)) >> 16);  // RNE
}
__device__ __forceinline__ float softplusf(float v) {
    return __logf(1.f + __expf(v));
}

// Prepack to bf16 in ws: dyn h-weights [256 u][256 k] at ws[0..65535],
// W_x [512 out][64 k] at ws[65536..98303].
__global__ __launch_bounds__(256) void prepack_kernel(const float* __restrict__ W_gd,
                                                      unsigned short* __restrict__ ws) {
    int i = blockIdx.x * 256 + threadIdx.x;                     // 0..65535
    ws[i] = f2bf(W_gd[(256 + (i >> 8)) * 320 + 64 + (i & 255)]);
    if (i < 32768) ws[65536 + i] = f2bf(W_gd[(i >> 6) * 320 + (i & 63)]);
}

// B=512, S=128, I=64, H=256, C=10
// 256 blocks (2 batch rows) x 512 threads (8 waves), 1 block/CU.
// Partition (VGPR cap 128 = 65536/blockDim, R1-R6): regs = gate 64 + pipe 20;
// LDS = tau 128K (4-bit XOR swz) + dyn-chunk0(uA units) 8K + bufs; L2 = 15
// bf16x8 frags/stage streamed through a 5-deep rotating FIFO (distance 5
// iters ~300cy > L2 latency). abuf ping-pong -> 1 barrier/stage (R8: 2).
__global__ __launch_bounds__(512, 1)
void ltc_kernel(
    const float* __restrict__ x, const float* __restrict__ W_gd,
    const float* __restrict__ b_gd, const float* __restrict__ W_tau,
    const float* __restrict__ b_tau, const float* __restrict__ gleak,
    const float* __restrict__ cm, const float* __restrict__ W_fc,
    const float* __restrict__ b_fc, const unsigned short* __restrict__ ws,
    float* __restrict__ out)
{
    const int tid  = threadIdx.x;
    const int lane = tid & 63;
    const int wv   = tid >> 6;          // wave 0..7, owns units 32*wv..32*wv+31
    const int c16  = lane & 15;
    const int kg   = lane >> 4;
    const int kg8  = kg * 8;
    const int row0 = blockIdx.x * 2;

    __shared__ __align__(16) unsigned short tauL[65536];       // tau, 4-bit swizzle
    __shared__ __align__(16) unsigned short dynL[4096];        // dyn chunk0, uA-type units only
    __shared__ __align__(16) unsigned short abuf[2][2][264];   // ping-pong h_eff [p][row][u]
    __shared__ __align__(16) unsigned short xbuf[2][72];
    __shared__ __align__(8)  float tcL[512];                   // {b_tau, cden}
    __shared__ float bgdL[512];
    __shared__ float hout[2][257];

    // ---- LDS fills ----
    for (int i = tid; i < 65536; i += 512) {
        int u = i >> 8, k = i & 255;
        tauL[u * 256 + (k ^ ((u & 15) << 3))] = f2bf(W_tau[i]);
    }
    for (int i = tid; i < 4096; i += 512) {                    // uidx = wv*16+c16 <-> u = 32wv+c16
        int uidx = i >> 5, k = i & 31;
        int u = (uidx >> 4) * 32 + (uidx & 15);
        dynL[uidx * 32 + (k ^ ((uidx & 3) << 3))] = f2bf(W_gd[(256 + u) * 320 + 64 + k]);
    }
    for (int i = tid; i < 2 * 2 * 264; i += 512) ((unsigned short*)abuf)[i] = 0;
    if (tid < 256) {
        tcL[2 * tid]     = b_tau[tid];
        tcL[2 * tid + 1] = softplusf(cm[tid]) + softplusf(gleak[tid]) + 1e-6f;
    }
    bgdL[tid] = b_gd[tid];

    const int uA = 32 * wv + c16;
    const int uB = uA + 16;
    const int tswz = c16 << 3;
    const unsigned short* tAb = tauL + uA * 256;
    const unsigned short* tBb = tauL + uB * 256;
    const bf16x8* dA0p = (const bf16x8*)(dynL + (wv * 16 + c16) * 32 + (kg8 ^ ((c16 & 3) << 3)));
    const int vOffA = uA * 256 + kg8;       // element offsets into ws (saddr-form loads)
    const int vOffB = vOffA + 16 * 256;
    const int vOffX = 65536 + uA * 64 + kg8;

    // ---- gate weights into registers (64 VGPR) ----
    bf16x8 Wg[2][8];
    {
        const int wrow[2] = { uA, uB };
        #pragma unroll
        for (int t = 0; t < 2; ++t) {
            const float* src = W_gd + wrow[t] * 320 + 64;
            #pragma unroll
            for (int s = 0; s < 8; ++s) {
                const float4* p = (const float4*)(src + s * 32 + kg8);
                float4 a = p[0], b = p[1];
                bf16x8 v;
                v[0] = (short)f2bf(a.x); v[1] = (short)f2bf(a.y);
                v[2] = (short)f2bf(a.z); v[3] = (short)f2bf(a.w);
                v[4] = (short)f2bf(b.x); v[5] = (short)f2bf(b.y);
                v[6] = (short)f2bf(b.z); v[7] = (short)f2bf(b.w);
                Wg[t][s] = v;
            }
        }
    }

    const int rsel = (c16 < 2) ? c16 : 0;
    const unsigned short* aptrP0 = &abuf[0][rsel][kg8];
    const unsigned short* aptrP1 = &abuf[1][rsel][kg8];
    const unsigned short* xptr   = &xbuf[rsel][kg8];

    float hv[2][2] = {{0.f, 0.f}, {0.f, 0.f}};
    f16x2 zh; zh[0] = (_Float16)0.f; zh[1] = (_Float16)0.f;
    f16x2 kk1[2] = { zh, zh }, kk2[2] = { zh, zh }, kk3[2] = { zh, zh };

    // ---- FIFO prologue: slots 0..4 <- frags 0..4 = uA s=1..5 ----
    bf16x8 pipe[5];
    #pragma unroll
    for (int i = 0; i < 5; ++i)
        pipe[i] = *(const bf16x8*)(ws + vOffA + (i + 1) * 32);

    __syncthreads();

#define ELEM(ti, G, D, den, en)                                                  \
    _Pragma("unroll")                                                            \
    for (int r = 0; r < 2; ++r) {                                                \
        float gate = G[r] + (float)gdx[ti][r];                                   \
        float dyn  = D[r] + (float)gdx[2 + ti][r];                               \
        float sig = __fdividef(1.f, 1.f + __expf(-gate));                        \
        float th  = 1.f - __fdividef(2.f, __expf(2.f * dyn) + 1.f);              \
        float k1v = (float)kk1[ti][r], k2v = (float)kk2[ti][r], k3v = (float)kk3[ti][r]; \
        float h0 = hv[ti][r];                                                    \
        float ec;                                                                \
        if      (stg == 0) ec = h0;                                              \
        else if (stg == 1) ec = h0 + k1v * (1.f / 3.f);                          \
        else if (stg == 2) ec = h0 - k1v * (1.f / 3.f) + k2v;                    \
        else               ec = h0 + k1v - k2v + k3v;                            \
        float kv = __fdividef(sig * th - ec, den[r]);                            \
        if (stg == 0)      { kk1[ti][r] = (_Float16)kv; en[r] = h0 + kv * (1.f / 3.f); } \
        else if (stg == 1) { kk2[ti][r] = (_Float16)kv; en[r] = h0 - k1v * (1.f / 3.f) + kv; } \
        else if (stg == 2) { kk3[ti][r] = (_Float16)kv; en[r] = h0 + k1v - k2v + kv; } \
        else               { en[r] = h0 + 0.125f * (k1v + 3.f * (k2v + k3v) + kv); hv[ti][r] = en[r]; } \
    }

    #pragma unroll 1
    for (int ts = 0; ts < 128; ++ts) {
        if (tid < 128) {
            int r = tid >> 6, i = tid & 63;
            xbuf[r][i] = f2bf(x[((row0 + r) * 128 + ts) * 64 + i]);
        }
        __syncthreads();

        // ---- x-part GEMM ----
        f32x4 gx0 = {0,0,0,0}, gx1 = {0,0,0,0}, gx2 = {0,0,0,0}, gx3 = {0,0,0,0};
        #pragma unroll
        for (int s = 0; s < 2; ++s) {
            bf16x8 ax = *(const bf16x8*)(xptr + s * 32);
            gx0 = MFMA(ax, *(const bf16x8*)(ws + vOffX + s * 32), gx0);
            gx1 = MFMA(ax, *(const bf16x8*)(ws + vOffX + 16 * 64 + s * 32), gx1);
            gx2 = MFMA(ax, *(const bf16x8*)(ws + vOffX + 256 * 64 + s * 32), gx2);
            gx3 = MFMA(ax, *(const bf16x8*)(ws + vOffX + 272 * 64 + s * 32), gx3);
        }
        f16x2 gdx[4];
        {
            float bg0 = bgdL[uA], bg1 = bgdL[uB], bg2 = bgdL[256 + uA], bg3 = bgdL[256 + uB];
            gdx[0][0] = (_Float16)(gx0[0] + bg0); gdx[0][1] = (_Float16)(gx0[1] + bg0);
            gdx[1][0] = (_Float16)(gx1[0] + bg1); gdx[1][1] = (_Float16)(gx1[1] + bg1);
            gdx[2][0] = (_Float16)(gx2[0] + bg2); gdx[2][1] = (_Float16)(gx2[1] + bg2);
            gdx[3][0] = (_Float16)(gx3[0] + bg3); gdx[3][1] = (_Float16)(gx3[1] + bg3);
        }

        // ---- 4 RK stages; read abuf[stg&1], write abuf[1-(stg&1)], 1 barrier ----
        #pragma unroll
        for (int stg = 0; stg < 4; ++stg) {
            const unsigned short* aptr = (stg & 1) ? aptrP1 : aptrP0;
            unsigned short (*wbuf)[264] = abuf[(stg & 1) ^ 1];

            // ---- uA sweep ----
            f32x4 T0 = {0,0,0,0}, G0 = {0,0,0,0}, D0 = {0,0,0,0};
            {
                bf16x8 A = *(const bf16x8*)(aptr);
                T0 = MFMA(A, *(const bf16x8*)(tAb + (kg8 ^ tswz)), T0);
                G0 = MFMA(A, Wg[0][0], G0);
                D0 = MFMA(A, *dA0p, D0);
            }
            #pragma unroll
            for (int s = 1; s < 8; ++s) {
                bf16x8 A = *(const bf16x8*)(aptr + s * 32);
                T0 = MFMA(A, *(const bf16x8*)(tAb + ((s * 32 + kg8) ^ tswz)), T0);
                G0 = MFMA(A, Wg[0][s], G0);
                D0 = MFMA(A, pipe[(s - 1) % 5], D0);
                // refill slot with frag (s-1)+5: s<=2 -> uA chunk s+5; else uB chunk s-3
                if (s <= 2) pipe[(s - 1) % 5] = *(const bf16x8*)(ws + vOffA + (s + 5) * 32);
                else        pipe[(s - 1) % 5] = *(const bf16x8*)(ws + vOffB + (s - 3) * 32);
            }
            float2 tc0 = *(const float2*)(tcL + 2 * uA);
            float den0[2];
            den0[0] = softplusf(T0[0] + tc0.x) + tc0.y;
            den0[1] = softplusf(T0[1] + tc0.x) + tc0.y;
            float en0[2];
            ELEM(0, G0, D0, den0, en0);
            if (lane < 16) { wbuf[0][uA] = f2bf(en0[0]); wbuf[1][uA] = f2bf(en0[1]); }

            // ---- uB sweep (dyn fully streamed: frags 7..14 = uB s=0..7) ----
            f32x4 T1 = {0,0,0,0}, G1 = {0,0,0,0}, D1 = {0,0,0,0};
            #pragma unroll
            for (int s = 0; s < 8; ++s) {
                bf16x8 A = *(const bf16x8*)(aptr + s * 32);
                T1 = MFMA(A, *(const bf16x8*)(tBb + ((s * 32 + kg8) ^ tswz)), T1);
                G1 = MFMA(A, Wg[1][s], G1);
                D1 = MFMA(A, pipe[(7 + s) % 5], D1);
                // refill with frag (7+s)+5 = 12+s: s<=2 -> uB chunk 5+s; else next-stage uA chunk s-2
                if (s <= 2) pipe[(7 + s) % 5] = *(const bf16x8*)(ws + vOffB + (5 + s) * 32);
                else        pipe[(7 + s) % 5] = *(const bf16x8*)(ws + vOffA + (s - 2) * 32);
            }
            float2 tc1 = *(const float2*)(tcL + 2 * uB);
            float den1[2];
            den1[0] = softplusf(T1[0] + tc1.x) + tc1.y;
            den1[1] = softplusf(T1[1] + tc1.x) + tc1.y;
            float en1[2];
            ELEM(1, G1, D1, den1, en1);
            if (lane < 16) { wbuf[0][uB] = f2bf(en1[0]); wbuf[1][uB] = f2bf(en1[1]); }

            __syncthreads();   // write-buffer visible; read-buffer was never written
        }
    }
#undef ELEM

    // ---- epilogue: out = h @ W_fc^T + b_fc ----
    if (lane < 16) {
        hout[0][uA] = hv[0][0]; hout[1][uA] = hv[0][1];
        hout[0][uB] = hv[1][0]; hout[1][uB] = hv[1][1];
    }
    __syncthreads();
    if (tid < 20) {
        int r = tid / 10, c = tid % 10;
        float acc = b_fc[c];
        for (int k = 0; k < 256; ++k) acc = fmaf(hout[r][k], W_fc[c * 256 + k], acc);
        out[(row0 + r) * 10 + c] = acc;
    }
}

extern "C" void kernel_launch(void* const* d_in, const int* in_sizes, int n_in,
                              void* d_out, int out_size, void* d_ws, size_t ws_size,
                              hipStream_t stream) {
    (void)in_sizes; (void)n_in; (void)out_size; (void)ws_size;
    unsigned short* ws16 = (unsigned short*)d_ws;
    prepack_kernel<<<256, 256, 0, stream>>>((const float*)d_in[1], ws16);
    ltc_kernel<<<256, 512, 0, stream>>>(
        (const float*)d_in[0], (const float*)d_in[1], (const float*)d_in[2],
        (const float*)d_in[3], (const float*)d_in[4], (const float*)d_in[5],
        (const float*)d_in[6], (const float*)d_in[7], (const float*)d_in[8],
        ws16, (float*)d_out);
}